// Round 9
// baseline (374.814 us; speedup 1.0000x reference)
//
#include <hip/hip_runtime.h>

typedef unsigned short u16;
typedef __bf16 bf16x8 __attribute__((ext_vector_type(8)));
typedef u16 u16x8 __attribute__((ext_vector_type(8)));
typedef u16 u16x4 __attribute__((ext_vector_type(4)));
typedef float f32x4 __attribute__((ext_vector_type(4)));

__device__ __forceinline__ u16 f2bf(float f) {
    union { float f; unsigned int u; } x; x.f = f;
    unsigned int r = x.u + 0x7FFFu + ((x.u >> 16) & 1u);
    return (u16)(r >> 16);
}

// hardware f32->bf16 (RTNE fptrunc; gfx950 has native cvt)
__device__ __forceinline__ u16 f2bf_hw(float f) {
    union { __bf16 b; u16 u; } x; x.b = (__bf16)f; return x.u;
}

// async global -> LDS, 16B per lane. LDS dest is wave-uniform base + lane*16.
__device__ __forceinline__ void gload_lds16(const u16* g, u16* l) {
    __builtin_amdgcn_global_load_lds(
        (const __attribute__((address_space(1))) unsigned int*)g,
        (__attribute__((address_space(3))) unsigned int*)l, 16, 0, 0);
}

// ---------------- weight repack (LDS-tiled, coalesced both sides) ----------------

// QKV: out[n][d], n = wsel*1024 + h*64 + kk ; src W[h][d][kk]. 64d x 64kk tiles.
// Wq pre-scaled by 0.125*log2(e) (exp2-domain softmax).
__global__ __launch_bounds__(256) void qkvT_k(
    const float* __restrict__ Wq, const float* __restrict__ Wk,
    const float* __restrict__ Wv, u16* __restrict__ out)
{
    __shared__ float T[64][65];
    const int d0 = blockIdx.x * 64;
    const int y = blockIdx.y;          // 0..47
    const int wsel = y >> 4, h = y & 15;
    const float* W = (wsel == 0) ? Wq : (wsel == 1) ? Wk : Wv;
    const float scale = (wsel == 0) ? 0.125f * 1.44269504088896f : 1.0f;
    const int tid = threadIdx.x;
    const int tr = tid >> 4;           // 0..15
    const int tc = (tid & 15) * 4;     // 0..60
    #pragma unroll
    for (int k = 0; k < 4; k++) {
        f32x4 v = *(const f32x4*)(W + (size_t)h * 65536 + (size_t)(d0 + 16 * k + tr) * 64 + tc);
        T[16 * k + tr][tc]     = v[0];
        T[16 * k + tr][tc + 1] = v[1];
        T[16 * k + tr][tc + 2] = v[2];
        T[16 * k + tr][tc + 3] = v[3];
    }
    __syncthreads();
    #pragma unroll
    for (int k = 0; k < 4; k++) {
        const int kk = 16 * k + tr;
        u16x4 o;
        #pragma unroll
        for (int i = 0; i < 4; i++) o[i] = f2bf(T[tc + i][kk] * scale);
        *(u16x4*)(out + (size_t)(wsel * 1024 + h * 64 + kk) * 1024 + d0 + tc) = o;
    }
}

// out (R x C bf16) = transpose(in (C x R f32)). 64x64 tiles via LDS.
__global__ __launch_bounds__(256) void transT_k(
    const float* __restrict__ in, u16* __restrict__ out, int R, int C)
{
    __shared__ float T[64][65];
    const int r0 = blockIdx.x * 64, c0 = blockIdx.y * 64;
    const int tid = threadIdx.x;
    const int tr = tid >> 4;
    const int tc = (tid & 15) * 4;
    #pragma unroll
    for (int k = 0; k < 4; k++) {
        f32x4 v = *(const f32x4*)(in + (size_t)(c0 + 16 * k + tr) * R + r0 + tc);
        T[16 * k + tr][tc]     = v[0];
        T[16 * k + tr][tc + 1] = v[1];
        T[16 * k + tr][tc + 2] = v[2];
        T[16 * k + tr][tc + 3] = v[3];
    }
    __syncthreads();
    #pragma unroll
    for (int k = 0; k < 4; k++) {
        const int rl = 16 * k + tr;
        u16x4 o;
        #pragma unroll
        for (int i = 0; i < 4; i++) o[i] = f2bf(T[tc + i][rl]);
        *(u16x4*)(out + (size_t)(r0 + rl) * C + c0 + tc) = o;
    }
}

// V^T: vT[(b*16+h)*64 + d][s] = qkvB[s*2+b][2048 + h*64 + d]
__global__ __launch_bounds__(256) void vtrans_k(const u16* __restrict__ qkv, u16* __restrict__ vT)
{
    __shared__ u16 T[64][72];
    const int bh = blockIdx.x, b = bh >> 4, h = bh & 15;
    const int s0 = blockIdx.y * 64;
    const int tid = threadIdx.x;
    const int r = tid >> 2, c0 = (tid & 3) * 16;
    const u16* src = qkv + ((size_t)((s0 + r) * 2 + b)) * 3072 + 2048 + h * 64 + c0;
    *(u16x8*)&T[r][c0] = *(const u16x8*)src;
    *(u16x8*)&T[r][c0 + 8] = *(const u16x8*)(src + 8);
    __syncthreads();
    u16x8 o0, o1;
    #pragma unroll
    for (int i = 0; i < 8; i++) o0[i] = T[c0 + i][r];
    #pragma unroll
    for (int i = 0; i < 8; i++) o1[i] = T[c0 + 8 + i][r];
    u16* dst = vT + (size_t)(bh * 64 + r) * 2048 + s0 + c0;
    *(u16x8*)dst = o0;
    *(u16x8*)(dst + 8) = o1;
}

// ---------------- rmsnorm ----------------
__global__ __launch_bounds__(256) void rmsnorm_k(
    const float* __restrict__ x, const float* __restrict__ g, u16* __restrict__ out)
{
    const int row = blockIdx.x;
    const int tid = threadIdx.x;
    const float* xr = x + (size_t)row * 1024;
    f32x4 v = *(const f32x4*)(xr + tid * 4);
    float ss = v[0] * v[0] + v[1] * v[1] + v[2] * v[2] + v[3] * v[3];
    #pragma unroll
    for (int off = 32; off > 0; off >>= 1) ss += __shfl_down(ss, off);
    __shared__ float red[4];
    if ((tid & 63) == 0) red[tid >> 6] = ss;
    __syncthreads();
    float sum = red[0] + red[1] + red[2] + red[3];
    float rinv = rsqrtf(sum * (1.0f / 1024.0f) + 1e-6f);
    f32x4 gv = *(const f32x4*)(g + tid * 4);
    u16x4 o;
    #pragma unroll
    for (int i = 0; i < 4; i++) o[i] = f2bf(v[i] * gv[i] * rinv);
    *(u16x4*)(out + (size_t)row * 1024 + tid * 4) = o;
}

// xout = res + p0 + p1 ; hout = rmsnorm(xout)*g   (block = one 1024-wide row)
__global__ __launch_bounds__(256) void addred_norm_k(
    const float* __restrict__ res, const float* __restrict__ p0,
    const float* __restrict__ p1, const float* __restrict__ g,
    float* __restrict__ xout, u16* __restrict__ hout)
{
    const int row = blockIdx.x;
    const int tid = threadIdx.x;
    const size_t base = (size_t)row * 1024 + tid * 4;
    f32x4 a = *(const f32x4*)(res + base);
    f32x4 b = *(const f32x4*)(p0 + base);
    f32x4 c = *(const f32x4*)(p1 + base);
    f32x4 o = a + b + c;
    *(f32x4*)(xout + base) = o;
    float ss = o[0] * o[0] + o[1] * o[1] + o[2] * o[2] + o[3] * o[3];
    #pragma unroll
    for (int off = 32; off > 0; off >>= 1) ss += __shfl_down(ss, off);
    __shared__ float red[4];
    if ((tid & 63) == 0) red[tid >> 6] = ss;
    __syncthreads();
    float sum = red[0] + red[1] + red[2] + red[3];
    float rinv = rsqrtf(sum * (1.0f / 1024.0f) + 1e-6f);
    f32x4 gv = *(const f32x4*)(g + tid * 4);
    u16x4 hv;
    #pragma unroll
    for (int i = 0; i < 4; i++) hv[i] = f2bf(o[i] * gv[i] * rinv);
    *(u16x4*)(hout + base) = hv;
}

// out = res + p0 + p1 (all f32)
__global__ __launch_bounds__(256) void addred_k(
    const float* __restrict__ res, const float* __restrict__ p0,
    const float* __restrict__ p1, float* __restrict__ out)
{
    int i = (blockIdx.x * 256 + threadIdx.x) * 4;
    f32x4 a = *(const f32x4*)(res + i);
    f32x4 b = *(const f32x4*)(p0 + i);
    f32x4 c = *(const f32x4*)(p1 + i);
    f32x4 o = a + b + c;
    *(f32x4*)(out + i) = o;
}

// ---------------- GEMM: C = A(MxK) * BT(NxK)^T, bf16 in, fp32 acc ----------------
// Block tile 128 x BN (BN=128: wave 64x64, acc 4x4; BN=256: wave 64x128, acc 4x8 —
// LDS reads/MFMA drop 0.5->0.375 and MFMA per barrier window doubles).
// BK=64; XOR block swizzle on LDS (2-way banks); XCD band swizzle (gridDim.y==32,
// M=4096): XCD r = bid%8 owns m-band [4r,4r+4), n slow -> A band L2-resident.
// MODE 0: store bf16 ; MODE 1: outF = res + v ; MODE 2: bf16 silu(v) ; MODE 3: f32 partial
template <int MODE, int BN>
__global__ __launch_bounds__(256) void gemm_bt_k(
    const u16* __restrict__ A, const u16* __restrict__ BT,
    u16* __restrict__ outB, float* __restrict__ outF, const float* __restrict__ res,
    int M, int N, int K, int klen)
{
    constexpr int JN = BN / 32;        // B j-tiles per wave (4 or 8)
    __shared__ u16 As[128 * 64];       // 16 KB
    __shared__ u16 Bs[BN * 64];        // 16 or 32 KB
    const int tid = threadIdx.x;
    const int lane = tid & 63, w = tid >> 6;
    const int wm = w >> 1, wn = w & 1;
    const int quad = lane >> 4, l15 = lane & 15;
    const int bid = blockIdx.x + gridDim.x * blockIdx.y;
    const int bj = bid >> 3;
    const int m0 = ((bid & 7) * 4 + (bj & 3)) * 128;   // m-band per XCD
    const int n0 = (bj >> 2) * BN;                     // n slow
    const int kbeg = blockIdx.z * klen;

    f32x4 acc[4][JN] = {};

    const int srow = (w << 3) + (lane >> 3);
    const int swz = ((lane & 7) ^ (lane >> 3)) << 3;
    const u16* aA = A + (size_t)(m0 + srow) * K + kbeg + swz;
    const u16* aB = BT + (size_t)(n0 + srow) * K + kbeg + swz;
    u16* lA = As + w * 512;
    u16* lB = Bs + w * 512;
    const int rsw = (l15 & 7) << 3;   // read-side unswizzle

    for (int k0 = 0; k0 < klen; k0 += 64) {
        __syncthreads();
        #pragma unroll
        for (int c = 0; c < 4; c++)
            gload_lds16(aA + (size_t)(c * 32) * K + k0, lA + c * 2048);
        #pragma unroll
        for (int c = 0; c < BN / 32; c++)
            gload_lds16(aB + (size_t)(c * 32) * K + k0, lB + c * 2048);
        __syncthreads();
        #pragma unroll
        for (int kh = 0; kh < 2; kh++) {
            const int cb = ((kh * 4 + quad) << 3);
            bf16x8 af[4], bfr[JN];
            #pragma unroll
            for (int i = 0; i < 4; i++)
                af[i] = *(const bf16x8*)(As + (wm * 64 + i * 16 + l15) * 64 + (cb ^ rsw));
            #pragma unroll
            for (int j = 0; j < JN; j++)
                bfr[j] = *(const bf16x8*)(Bs + (wn * (BN / 2) + j * 16 + l15) * 64 + (cb ^ rsw));
            #pragma unroll
            for (int i = 0; i < 4; i++)
                #pragma unroll
                for (int j = 0; j < JN; j++)
                    acc[i][j] = __builtin_amdgcn_mfma_f32_16x16x32_bf16(af[i], bfr[j], acc[i][j], 0, 0, 0);
        }
    }

    float* outFz = (MODE == 3) ? outF + (size_t)blockIdx.z * M * N : outF;
    #pragma unroll
    for (int i = 0; i < 4; i++) {
        const int row = m0 + wm * 64 + i * 16 + quad * 4;
        #pragma unroll
        for (int j = 0; j < JN; j++) {
            const int col = n0 + wn * (BN / 2) + j * 16 + l15;
            #pragma unroll
            for (int r = 0; r < 4; r++) {
                const size_t idx = (size_t)(row + r) * N + col;
                float v = acc[i][j][r];
                if (MODE == 0) {
                    outB[idx] = f2bf_hw(v);
                } else if (MODE == 1) {
                    outF[idx] = res[idx] + v;
                } else if (MODE == 2) {
                    // silu via exp2 + hw rcp (bf16 output precision)
                    float e = exp2f(v * -1.44269504088896f);
                    outB[idx] = f2bf_hw(v * __builtin_amdgcn_rcpf(1.0f + e));
                } else {
                    outFz[idx] = v;
                }
            }
        }
    }
}

// ---------------- flash attention ----------------
// qkv rows s*2+b, cols [Q|K|V]; Q pre-scaled by 0.125*log2e. vT rows bh*64+d, cols s.
// XOR-swizzled K/V LDS (2-way banks), double-buffered tiles, no-max exp2 softmax.
// Row-sum l via ones-MFMA (l = P·1, same C-layout rows as o). HW bf16 cvt.
__global__ __launch_bounds__(256) void attn_k(const u16* __restrict__ qkv,
                                              const u16* __restrict__ vT,
                                              u16* __restrict__ ctx)
{
    const int bh = blockIdx.x;
    const int qt = 31 - (int)blockIdx.y;
    const int b = bh >> 4, h = bh & 15;
    const int q0 = qt * 64;
    const int tid = threadIdx.x;
    const int lane = tid & 63, w = tid >> 6;
    const int quad = lane >> 4, l15 = lane & 15;

    __shared__ u16 QP[64][72];
    __shared__ u16 Ks[2][4096];
    __shared__ u16 Vs[2][4096];

    {
        const int r = tid >> 2, c0 = (tid & 3) * 16;
        const u16* src = qkv + ((size_t)((q0 + r) * 2 + b)) * 3072 + h * 64 + c0;
        *(u16x8*)&QP[r][c0] = *(const u16x8*)(src);
        *(u16x8*)&QP[r][c0 + 8] = *(const u16x8*)(src + 8);
    }
    __syncthreads();

    const bf16x8 aq0 = *(const bf16x8*)&QP[16 * w + l15][quad * 8];
    const bf16x8 aq1 = *(const bf16x8*)&QP[16 * w + l15][32 + quad * 8];

    bf16x8 ones;
    #pragma unroll
    for (int i = 0; i < 8; i++) ones[i] = (__bf16)1.0f;

    const int kr = (w << 3) + (lane >> 3);
    const int swz = ((lane & 7) ^ (lane >> 3)) << 3;
    const int ldsoff = w * 512;
    const u16* kbase0 = qkv + ((size_t)(kr * 2 + b)) * 3072 + 1024 + h * 64 + swz;
    const u16* kbase1 = kbase0 + (size_t)32 * 2 * 3072;
    const u16* vrow0 = vT + (size_t)(bh * 64 + kr) * 2048 + swz;
    const u16* vrow1 = vrow0 + (size_t)32 * 2048;

    const int rsw = (l15 & 7) << 3;

    f32x4 o[4] = {};
    f32x4 accl = {};

    gload_lds16(kbase0, &Ks[0][0] + ldsoff);
    gload_lds16(kbase1, &Ks[0][0] + 2048 + ldsoff);
    gload_lds16(vrow0, &Vs[0][0] + ldsoff);
    gload_lds16(vrow1, &Vs[0][0] + 2048 + ldsoff);

    int cur = 0;
    for (int t0 = 0; t0 <= q0; t0 += 64) {
        __syncthreads();
        if (t0 + 64 <= q0) {
            const size_t go = (size_t)(t0 + 64) * 2 * 3072;
            u16* KB = &Ks[cur ^ 1][0];
            u16* VB = &Vs[cur ^ 1][0];
            gload_lds16(kbase0 + go, KB + ldsoff);
            gload_lds16(kbase1 + go, KB + 2048 + ldsoff);
            gload_lds16(vrow0 + (t0 + 64), VB + ldsoff);
            gload_lds16(vrow1 + (t0 + 64), VB + 2048 + ldsoff);
        }
        const u16* KB = &Ks[cur][0];
        const u16* VB = &Vs[cur][0];

        f32x4 s[4];
        #pragma unroll
        for (int j = 0; j < 4; j++) {
            const u16* kb = KB + (j * 16 + l15) * 64;
            bf16x8 bk0 = *(const bf16x8*)(kb + (((quad << 3) ^ rsw)));
            bf16x8 bk1 = *(const bf16x8*)(kb + ((((quad + 4) << 3) ^ rsw)));
            f32x4 c = {};
            c = __builtin_amdgcn_mfma_f32_16x16x32_bf16(aq0, bk0, c, 0, 0, 0);
            c = __builtin_amdgcn_mfma_f32_16x16x32_bf16(aq1, bk1, c, 0, 0, 0);
            s[j] = c;
        }

        if (t0 == q0) {
            #pragma unroll
            for (int j = 0; j < 4; j++)
                #pragma unroll
                for (int r = 0; r < 4; r++)
                    if ((j * 16 + l15) > (16 * w + quad * 4 + r)) s[j][r] = -1e30f;
        }

        #pragma unroll
        for (int j = 0; j < 4; j++)
            #pragma unroll
            for (int r = 0; r < 4; r++)
                QP[16 * w + quad * 4 + r][j * 16 + l15] = f2bf_hw(exp2f(s[j][r]));

        bf16x8 ap0 = *(const bf16x8*)&QP[16 * w + l15][quad * 8];
        bf16x8 ap1 = *(const bf16x8*)&QP[16 * w + l15][32 + quad * 8];
        accl = __builtin_amdgcn_mfma_f32_16x16x32_bf16(ap0, ones, accl, 0, 0, 0);
        accl = __builtin_amdgcn_mfma_f32_16x16x32_bf16(ap1, ones, accl, 0, 0, 0);
        #pragma unroll
        for (int j = 0; j < 4; j++) {
            const u16* vb = VB + (j * 16 + l15) * 64;
            bf16x8 bv0 = *(const bf16x8*)(vb + (((quad << 3) ^ rsw)));
            bf16x8 bv1 = *(const bf16x8*)(vb + ((((quad + 4) << 3) ^ rsw)));
            o[j] = __builtin_amdgcn_mfma_f32_16x16x32_bf16(ap0, bv0, o[j], 0, 0, 0);
            o[j] = __builtin_amdgcn_mfma_f32_16x16x32_bf16(ap1, bv1, o[j], 0, 0, 0);
        }
        cur ^= 1;
    }

    f32x4 linv;
    #pragma unroll
    for (int r = 0; r < 4; r++) linv[r] = 1.0f / accl[r];
    #pragma unroll
    for (int j = 0; j < 4; j++)
        #pragma unroll
        for (int r = 0; r < 4; r++) {
            int q = q0 + 16 * w + quad * 4 + r;
            int col = h * 64 + j * 16 + l15;
            ctx[((size_t)q * 2 + b) * 1024 + col] = f2bf_hw(o[j][r] * linv[r]);
        }
}

// ---------------- launcher ----------------
extern "C" void kernel_launch(void* const* d_in, const int* in_sizes, int n_in,
                              void* d_out, int out_size, void* d_ws, size_t ws_size,
                              hipStream_t stream)
{
    (void)in_sizes; (void)n_in; (void)out_size; (void)ws_size;
    const float* x  = (const float*)d_in[0];
    const float* g1 = (const float*)d_in[1];
    const float* g2 = (const float*)d_in[2];
    const float* Wq = (const float*)d_in[3];
    const float* Wk = (const float*)d_in[4];
    const float* Wv = (const float*)d_in[5];
    const float* Wo = (const float*)d_in[6];
    const float* W1 = (const float*)d_in[7];
    const float* W2 = (const float*)d_in[8];
    float* out = (float*)d_out;

    char* ws = (char*)d_ws;
    u16*   bqkvT = (u16*)(ws);                    // 3072x1024 bf16
    u16*   woT   = (u16*)(ws + 6291456);          // 1024x1024 bf16
    u16*   w1T   = (u16*)(ws + 8388608);          // 4096x1024 bf16
    u16*   w2T   = (u16*)(ws + 16777216);         // 1024x4096 bf16
    u16*   h1    = (u16*)(ws + 25165824);         // 4096x1024 bf16 [dead after QKV gemm]
    u16*   qkvB  = (u16*)(ws + 33554432);         // 4096x3072 bf16 [dead after attn]
    u16*   ctxB  = (u16*)(ws + 58720256);         // 4096x1024 bf16
    float* xmid  = (float*)(ws + 67108864);       // 4096x1024 f32
    u16*   h2    = (u16*)(ws + 83886080);         // 4096x1024 bf16
    u16*   actB  = (u16*)(ws + 92274688);         // 4096x4096 bf16
    u16*   vT    = (u16*)(ws + 25165824);         // 8 MB, reuses h1 region
    float* part  = (float*)(ws + 25165824);       // W2 partials (h1+qkvB region)
    float* partO = (float*)(ws + 92274688);       // Wo partials (actB region)

    qkvT_k<<<dim3(16, 48), 256, 0, stream>>>(Wq, Wk, Wv, bqkvT);
    transT_k<<<dim3(16, 16), 256, 0, stream>>>(Wo, woT, 1024, 1024);
    transT_k<<<dim3(64, 16), 256, 0, stream>>>(W1, w1T, 4096, 1024);
    transT_k<<<dim3(16, 64), 256, 0, stream>>>(W2, w2T, 1024, 4096);

    rmsnorm_k<<<4096, 256, 0, stream>>>(x, g1, h1);

    // QKV: N=3072, 12 n-tiles of 256
    gemm_bt_k<0, 256><<<dim3(12, 32), 256, 0, stream>>>(h1, bqkvT, qkvB, nullptr, nullptr,
                                                        4096, 3072, 1024, 1024);
    vtrans_k<<<dim3(32, 32), 256, 0, stream>>>(qkvB, vT);
    attn_k<<<dim3(32, 32), 256, 0, stream>>>(qkvB, vT, ctxB);

    // Wo split-K=2 (N=1024, 128-tiles) -> partials, then fused add+rmsnorm
    gemm_bt_k<3, 128><<<dim3(8, 32, 2), 256, 0, stream>>>(ctxB, woT, nullptr, partO, nullptr,
                                                          4096, 1024, 1024, 512);
    addred_norm_k<<<4096, 256, 0, stream>>>(x, partO, partO + 4096 * 1024, g2, xmid, h2);

    // W1: N=4096, 16 n-tiles of 256
    gemm_bt_k<2, 256><<<dim3(16, 32), 256, 0, stream>>>(h2, w1T, actB, nullptr, nullptr,
                                                        4096, 4096, 1024, 1024);
    gemm_bt_k<3, 128><<<dim3(8, 32, 2), 256, 0, stream>>>(actB, w2T, nullptr, part, nullptr,
                                                          4096, 1024, 4096, 2048);
    addred_k<<<4096 * 1024 / 1024, 256, 0, stream>>>(xmid, part, part + 4096 * 1024, out);
}

// Round 10
// 326.776 us; speedup vs baseline: 1.1470x; 1.1470x over previous
//
#include <hip/hip_runtime.h>

typedef unsigned short u16;
typedef __bf16 bf16x8 __attribute__((ext_vector_type(8)));
typedef u16 u16x8 __attribute__((ext_vector_type(8)));
typedef u16 u16x4 __attribute__((ext_vector_type(4)));
typedef float f32x4 __attribute__((ext_vector_type(4)));

__device__ __forceinline__ u16 f2bf(float f) {
    union { float f; unsigned int u; } x; x.f = f;
    unsigned int r = x.u + 0x7FFFu + ((x.u >> 16) & 1u);
    return (u16)(r >> 16);
}

// hardware f32->bf16 (RTNE fptrunc; gfx950 has native cvt)
__device__ __forceinline__ u16 f2bf_hw(float f) {
    union { __bf16 b; u16 u; } x; x.b = (__bf16)f; return x.u;
}

// async global -> LDS, 16B per lane. LDS dest is wave-uniform base + lane*16.
__device__ __forceinline__ void gload_lds16(const u16* g, u16* l) {
    __builtin_amdgcn_global_load_lds(
        (const __attribute__((address_space(1))) unsigned int*)g,
        (__attribute__((address_space(3))) unsigned int*)l, 16, 0, 0);
}

// ---------------- weight repack (LDS-tiled, coalesced both sides) ----------------

// QKV: out[n][d], n = wsel*1024 + h*64 + kk ; src W[h][d][kk]. 64d x 64kk tiles.
// Wq pre-scaled by 0.125*log2(e) (exp2-domain softmax).
__global__ __launch_bounds__(256) void qkvT_k(
    const float* __restrict__ Wq, const float* __restrict__ Wk,
    const float* __restrict__ Wv, u16* __restrict__ out)
{
    __shared__ float T[64][65];
    const int d0 = blockIdx.x * 64;
    const int y = blockIdx.y;          // 0..47
    const int wsel = y >> 4, h = y & 15;
    const float* W = (wsel == 0) ? Wq : (wsel == 1) ? Wk : Wv;
    const float scale = (wsel == 0) ? 0.125f * 1.44269504088896f : 1.0f;
    const int tid = threadIdx.x;
    const int tr = tid >> 4;           // 0..15
    const int tc = (tid & 15) * 4;     // 0..60
    #pragma unroll
    for (int k = 0; k < 4; k++) {
        f32x4 v = *(const f32x4*)(W + (size_t)h * 65536 + (size_t)(d0 + 16 * k + tr) * 64 + tc);
        T[16 * k + tr][tc]     = v[0];
        T[16 * k + tr][tc + 1] = v[1];
        T[16 * k + tr][tc + 2] = v[2];
        T[16 * k + tr][tc + 3] = v[3];
    }
    __syncthreads();
    #pragma unroll
    for (int k = 0; k < 4; k++) {
        const int kk = 16 * k + tr;
        u16x4 o;
        #pragma unroll
        for (int i = 0; i < 4; i++) o[i] = f2bf(T[tc + i][kk] * scale);
        *(u16x4*)(out + (size_t)(wsel * 1024 + h * 64 + kk) * 1024 + d0 + tc) = o;
    }
}

// out (R x C bf16) = transpose(in (C x R f32)). 64x64 tiles via LDS.
__global__ __launch_bounds__(256) void transT_k(
    const float* __restrict__ in, u16* __restrict__ out, int R, int C)
{
    __shared__ float T[64][65];
    const int r0 = blockIdx.x * 64, c0 = blockIdx.y * 64;
    const int tid = threadIdx.x;
    const int tr = tid >> 4;
    const int tc = (tid & 15) * 4;
    #pragma unroll
    for (int k = 0; k < 4; k++) {
        f32x4 v = *(const f32x4*)(in + (size_t)(c0 + 16 * k + tr) * R + r0 + tc);
        T[16 * k + tr][tc]     = v[0];
        T[16 * k + tr][tc + 1] = v[1];
        T[16 * k + tr][tc + 2] = v[2];
        T[16 * k + tr][tc + 3] = v[3];
    }
    __syncthreads();
    #pragma unroll
    for (int k = 0; k < 4; k++) {
        const int rl = 16 * k + tr;
        u16x4 o;
        #pragma unroll
        for (int i = 0; i < 4; i++) o[i] = f2bf(T[tc + i][rl]);
        *(u16x4*)(out + (size_t)(r0 + rl) * C + c0 + tc) = o;
    }
}

// V^T: vT[(b*16+h)*64 + d][s] = qkvB[s*2+b][2048 + h*64 + d]
__global__ __launch_bounds__(256) void vtrans_k(const u16* __restrict__ qkv, u16* __restrict__ vT)
{
    __shared__ u16 T[64][72];
    const int bh = blockIdx.x, b = bh >> 4, h = bh & 15;
    const int s0 = blockIdx.y * 64;
    const int tid = threadIdx.x;
    const int r = tid >> 2, c0 = (tid & 3) * 16;
    const u16* src = qkv + ((size_t)((s0 + r) * 2 + b)) * 3072 + 2048 + h * 64 + c0;
    *(u16x8*)&T[r][c0] = *(const u16x8*)src;
    *(u16x8*)&T[r][c0 + 8] = *(const u16x8*)(src + 8);
    __syncthreads();
    u16x8 o0, o1;
    #pragma unroll
    for (int i = 0; i < 8; i++) o0[i] = T[c0 + i][r];
    #pragma unroll
    for (int i = 0; i < 8; i++) o1[i] = T[c0 + 8 + i][r];
    u16* dst = vT + (size_t)(bh * 64 + r) * 2048 + s0 + c0;
    *(u16x8*)dst = o0;
    *(u16x8*)(dst + 8) = o1;
}

// ---------------- rmsnorm ----------------
__global__ __launch_bounds__(256) void rmsnorm_k(
    const float* __restrict__ x, const float* __restrict__ g, u16* __restrict__ out)
{
    const int row = blockIdx.x;
    const int tid = threadIdx.x;
    const float* xr = x + (size_t)row * 1024;
    f32x4 v = *(const f32x4*)(xr + tid * 4);
    float ss = v[0] * v[0] + v[1] * v[1] + v[2] * v[2] + v[3] * v[3];
    #pragma unroll
    for (int off = 32; off > 0; off >>= 1) ss += __shfl_down(ss, off);
    __shared__ float red[4];
    if ((tid & 63) == 0) red[tid >> 6] = ss;
    __syncthreads();
    float sum = red[0] + red[1] + red[2] + red[3];
    float rinv = rsqrtf(sum * (1.0f / 1024.0f) + 1e-6f);
    f32x4 gv = *(const f32x4*)(g + tid * 4);
    u16x4 o;
    #pragma unroll
    for (int i = 0; i < 4; i++) o[i] = f2bf(v[i] * gv[i] * rinv);
    *(u16x4*)(out + (size_t)row * 1024 + tid * 4) = o;
}

// xout = res + p0 + p1 ; hout = rmsnorm(xout)*g   (block = one 1024-wide row)
__global__ __launch_bounds__(256) void addred_norm_k(
    const float* __restrict__ res, const float* __restrict__ p0,
    const float* __restrict__ p1, const float* __restrict__ g,
    float* __restrict__ xout, u16* __restrict__ hout)
{
    const int row = blockIdx.x;
    const int tid = threadIdx.x;
    const size_t base = (size_t)row * 1024 + tid * 4;
    f32x4 a = *(const f32x4*)(res + base);
    f32x4 b = *(const f32x4*)(p0 + base);
    f32x4 c = *(const f32x4*)(p1 + base);
    f32x4 o = a + b + c;
    *(f32x4*)(xout + base) = o;
    float ss = o[0] * o[0] + o[1] * o[1] + o[2] * o[2] + o[3] * o[3];
    #pragma unroll
    for (int off = 32; off > 0; off >>= 1) ss += __shfl_down(ss, off);
    __shared__ float red[4];
    if ((tid & 63) == 0) red[tid >> 6] = ss;
    __syncthreads();
    float sum = red[0] + red[1] + red[2] + red[3];
    float rinv = rsqrtf(sum * (1.0f / 1024.0f) + 1e-6f);
    f32x4 gv = *(const f32x4*)(g + tid * 4);
    u16x4 hv;
    #pragma unroll
    for (int i = 0; i < 4; i++) hv[i] = f2bf(o[i] * gv[i] * rinv);
    *(u16x4*)(hout + base) = hv;
}

// out = res + p0 + p1 (all f32)
__global__ __launch_bounds__(256) void addred_k(
    const float* __restrict__ res, const float* __restrict__ p0,
    const float* __restrict__ p1, float* __restrict__ out)
{
    int i = (blockIdx.x * 256 + threadIdx.x) * 4;
    f32x4 a = *(const f32x4*)(res + i);
    f32x4 b = *(const f32x4*)(p0 + i);
    f32x4 c = *(const f32x4*)(p1 + i);
    f32x4 o = a + b + c;
    *(f32x4*)(out + i) = o;
}

// ---------------- GEMM: C = A(MxK) * BT(NxK)^T, bf16 in, fp32 acc ----------------
// 128x128 block (BN=256 regressed: occupancy cliff — r9). BK=64, XOR block swizzle
// (2-way banks), XCD band swizzle. DOUBLE-BUFFERED K-loop (attn-verified pattern):
// one barrier per iter; prefetch buf^1 right after the barrier, compute buf —
// the vmcnt drain at the next barrier waits on loads aged a full compute window.
// MODE 0: store bf16 ; MODE 1: outF = res + v ; MODE 2: bf16 silu(v) ; MODE 3: f32 partial
template <int MODE>
__global__ __launch_bounds__(256) void gemm_bt_k(
    const u16* __restrict__ A, const u16* __restrict__ BT,
    u16* __restrict__ outB, float* __restrict__ outF, const float* __restrict__ res,
    int M, int N, int K, int klen)
{
    __shared__ u16 As[2][128 * 64];    // 2 x 16 KB
    __shared__ u16 Bs[2][128 * 64];    // 2 x 16 KB  (total 64 KB -> 2 blocks/CU)
    const int tid = threadIdx.x;
    const int lane = tid & 63, w = tid >> 6;
    const int wm = w >> 1, wn = w & 1;
    const int quad = lane >> 4, l15 = lane & 15;
    const int bid = blockIdx.x + gridDim.x * blockIdx.y;
    const int bj = bid >> 3;
    const int m0 = ((bid & 7) * 4 + (bj & 3)) * 128;   // m-band per XCD
    const int n0 = (bj >> 2) * 128;                    // n slow
    const int kbeg = blockIdx.z * klen;

    f32x4 acc[4][4] = {};

    const int srow = (w << 3) + (lane >> 3);
    const int swz = ((lane & 7) ^ (lane >> 3)) << 3;
    const u16* aA = A + (size_t)(m0 + srow) * K + kbeg + swz;
    const u16* aB = BT + (size_t)(n0 + srow) * K + kbeg + swz;
    const int wo = w * 512;
    const int rsw = (l15 & 7) << 3;   // read-side unswizzle

    // prologue: prefetch k0=0 into buffer 0
    #pragma unroll
    for (int c = 0; c < 4; c++) {
        gload_lds16(aA + (size_t)(c * 32) * K, &As[0][0] + c * 2048 + wo);
        gload_lds16(aB + (size_t)(c * 32) * K, &Bs[0][0] + c * 2048 + wo);
    }

    int cur = 0;
    for (int k0 = 0; k0 < klen; k0 += 64) {
        __syncthreads();   // buf[cur] loads drained; buf[cur^1] free (prev reads done)
        if (k0 + 64 < klen) {
            #pragma unroll
            for (int c = 0; c < 4; c++) {
                gload_lds16(aA + (size_t)(c * 32) * K + k0 + 64, &As[cur ^ 1][0] + c * 2048 + wo);
                gload_lds16(aB + (size_t)(c * 32) * K + k0 + 64, &Bs[cur ^ 1][0] + c * 2048 + wo);
            }
        }
        const u16* AB = &As[cur][0];
        const u16* BB = &Bs[cur][0];
        #pragma unroll
        for (int kh = 0; kh < 2; kh++) {
            const int cb = ((kh * 4 + quad) << 3);
            bf16x8 af[4], bfr[4];
            #pragma unroll
            for (int i = 0; i < 4; i++)
                af[i] = *(const bf16x8*)(AB + (wm * 64 + i * 16 + l15) * 64 + (cb ^ rsw));
            #pragma unroll
            for (int j = 0; j < 4; j++)
                bfr[j] = *(const bf16x8*)(BB + (wn * 64 + j * 16 + l15) * 64 + (cb ^ rsw));
            #pragma unroll
            for (int i = 0; i < 4; i++)
                #pragma unroll
                for (int j = 0; j < 4; j++)
                    acc[i][j] = __builtin_amdgcn_mfma_f32_16x16x32_bf16(af[i], bfr[j], acc[i][j], 0, 0, 0);
        }
        cur ^= 1;
    }

    float* outFz = (MODE == 3) ? outF + (size_t)blockIdx.z * M * N : outF;
    #pragma unroll
    for (int i = 0; i < 4; i++) {
        const int row = m0 + wm * 64 + i * 16 + quad * 4;
        #pragma unroll
        for (int j = 0; j < 4; j++) {
            const int col = n0 + wn * 64 + j * 16 + l15;
            #pragma unroll
            for (int r = 0; r < 4; r++) {
                const size_t idx = (size_t)(row + r) * N + col;
                float v = acc[i][j][r];
                if (MODE == 0) {
                    outB[idx] = f2bf_hw(v);
                } else if (MODE == 1) {
                    outF[idx] = res[idx] + v;
                } else if (MODE == 2) {
                    float e = exp2f(v * -1.44269504088896f);
                    outB[idx] = f2bf_hw(v * __builtin_amdgcn_rcpf(1.0f + e));
                } else {
                    outFz[idx] = v;
                }
            }
        }
    }
}

// ---------------- flash attention ----------------
// qkv rows s*2+b, cols [Q|K|V]; Q pre-scaled by 0.125*log2e. vT rows bh*64+d, cols s.
// XOR-swizzled K/V LDS (2-way banks), double-buffered tiles, no-max exp2 softmax.
// Row-sum l via ones-MFMA (l = P·1, same C-layout rows as o). HW bf16 cvt.
__global__ __launch_bounds__(256) void attn_k(const u16* __restrict__ qkv,
                                              const u16* __restrict__ vT,
                                              u16* __restrict__ ctx)
{
    const int bh = blockIdx.x;
    const int qt = 31 - (int)blockIdx.y;
    const int b = bh >> 4, h = bh & 15;
    const int q0 = qt * 64;
    const int tid = threadIdx.x;
    const int lane = tid & 63, w = tid >> 6;
    const int quad = lane >> 4, l15 = lane & 15;

    __shared__ u16 QP[64][72];
    __shared__ u16 Ks[2][4096];
    __shared__ u16 Vs[2][4096];

    {
        const int r = tid >> 2, c0 = (tid & 3) * 16;
        const u16* src = qkv + ((size_t)((q0 + r) * 2 + b)) * 3072 + h * 64 + c0;
        *(u16x8*)&QP[r][c0] = *(const u16x8*)(src);
        *(u16x8*)&QP[r][c0 + 8] = *(const u16x8*)(src + 8);
    }
    __syncthreads();

    const bf16x8 aq0 = *(const bf16x8*)&QP[16 * w + l15][quad * 8];
    const bf16x8 aq1 = *(const bf16x8*)&QP[16 * w + l15][32 + quad * 8];

    bf16x8 ones;
    #pragma unroll
    for (int i = 0; i < 8; i++) ones[i] = (__bf16)1.0f;

    const int kr = (w << 3) + (lane >> 3);
    const int swz = ((lane & 7) ^ (lane >> 3)) << 3;
    const int ldsoff = w * 512;
    const u16* kbase0 = qkv + ((size_t)(kr * 2 + b)) * 3072 + 1024 + h * 64 + swz;
    const u16* kbase1 = kbase0 + (size_t)32 * 2 * 3072;
    const u16* vrow0 = vT + (size_t)(bh * 64 + kr) * 2048 + swz;
    const u16* vrow1 = vrow0 + (size_t)32 * 2048;

    const int rsw = (l15 & 7) << 3;

    f32x4 o[4] = {};
    f32x4 accl = {};

    gload_lds16(kbase0, &Ks[0][0] + ldsoff);
    gload_lds16(kbase1, &Ks[0][0] + 2048 + ldsoff);
    gload_lds16(vrow0, &Vs[0][0] + ldsoff);
    gload_lds16(vrow1, &Vs[0][0] + 2048 + ldsoff);

    int cur = 0;
    for (int t0 = 0; t0 <= q0; t0 += 64) {
        __syncthreads();
        if (t0 + 64 <= q0) {
            const size_t go = (size_t)(t0 + 64) * 2 * 3072;
            u16* KB = &Ks[cur ^ 1][0];
            u16* VB = &Vs[cur ^ 1][0];
            gload_lds16(kbase0 + go, KB + ldsoff);
            gload_lds16(kbase1 + go, KB + 2048 + ldsoff);
            gload_lds16(vrow0 + (t0 + 64), VB + ldsoff);
            gload_lds16(vrow1 + (t0 + 64), VB + 2048 + ldsoff);
        }
        const u16* KB = &Ks[cur][0];
        const u16* VB = &Vs[cur][0];

        f32x4 s[4];
        #pragma unroll
        for (int j = 0; j < 4; j++) {
            const u16* kb = KB + (j * 16 + l15) * 64;
            bf16x8 bk0 = *(const bf16x8*)(kb + (((quad << 3) ^ rsw)));
            bf16x8 bk1 = *(const bf16x8*)(kb + ((((quad + 4) << 3) ^ rsw)));
            f32x4 c = {};
            c = __builtin_amdgcn_mfma_f32_16x16x32_bf16(aq0, bk0, c, 0, 0, 0);
            c = __builtin_amdgcn_mfma_f32_16x16x32_bf16(aq1, bk1, c, 0, 0, 0);
            s[j] = c;
        }

        if (t0 == q0) {
            #pragma unroll
            for (int j = 0; j < 4; j++)
                #pragma unroll
                for (int r = 0; r < 4; r++)
                    if ((j * 16 + l15) > (16 * w + quad * 4 + r)) s[j][r] = -1e30f;
        }

        #pragma unroll
        for (int j = 0; j < 4; j++)
            #pragma unroll
            for (int r = 0; r < 4; r++)
                QP[16 * w + quad * 4 + r][j * 16 + l15] = f2bf_hw(exp2f(s[j][r]));

        bf16x8 ap0 = *(const bf16x8*)&QP[16 * w + l15][quad * 8];
        bf16x8 ap1 = *(const bf16x8*)&QP[16 * w + l15][32 + quad * 8];
        accl = __builtin_amdgcn_mfma_f32_16x16x32_bf16(ap0, ones, accl, 0, 0, 0);
        accl = __builtin_amdgcn_mfma_f32_16x16x32_bf16(ap1, ones, accl, 0, 0, 0);
        #pragma unroll
        for (int j = 0; j < 4; j++) {
            const u16* vb = VB + (j * 16 + l15) * 64;
            bf16x8 bv0 = *(const bf16x8*)(vb + (((quad << 3) ^ rsw)));
            bf16x8 bv1 = *(const bf16x8*)(vb + ((((quad + 4) << 3) ^ rsw)));
            o[j] = __builtin_amdgcn_mfma_f32_16x16x32_bf16(ap0, bv0, o[j], 0, 0, 0);
            o[j] = __builtin_amdgcn_mfma_f32_16x16x32_bf16(ap1, bv1, o[j], 0, 0, 0);
        }
        cur ^= 1;
    }

    f32x4 linv;
    #pragma unroll
    for (int r = 0; r < 4; r++) linv[r] = 1.0f / accl[r];
    #pragma unroll
    for (int j = 0; j < 4; j++)
        #pragma unroll
        for (int r = 0; r < 4; r++) {
            int q = q0 + 16 * w + quad * 4 + r;
            int col = h * 64 + j * 16 + l15;
            ctx[((size_t)q * 2 + b) * 1024 + col] = f2bf_hw(o[j][r] * linv[r]);
        }
}

// ---------------- launcher ----------------
extern "C" void kernel_launch(void* const* d_in, const int* in_sizes, int n_in,
                              void* d_out, int out_size, void* d_ws, size_t ws_size,
                              hipStream_t stream)
{
    (void)in_sizes; (void)n_in; (void)out_size; (void)ws_size;
    const float* x  = (const float*)d_in[0];
    const float* g1 = (const float*)d_in[1];
    const float* g2 = (const float*)d_in[2];
    const float* Wq = (const float*)d_in[3];
    const float* Wk = (const float*)d_in[4];
    const float* Wv = (const float*)d_in[5];
    const float* Wo = (const float*)d_in[6];
    const float* W1 = (const float*)d_in[7];
    const float* W2 = (const float*)d_in[8];
    float* out = (float*)d_out;

    char* ws = (char*)d_ws;
    u16*   bqkvT = (u16*)(ws);                    // 3072x1024 bf16
    u16*   woT   = (u16*)(ws + 6291456);          // 1024x1024 bf16
    u16*   w1T   = (u16*)(ws + 8388608);          // 4096x1024 bf16
    u16*   w2T   = (u16*)(ws + 16777216);         // 1024x4096 bf16
    u16*   h1    = (u16*)(ws + 25165824);         // 4096x1024 bf16 [dead after QKV gemm]
    u16*   qkvB  = (u16*)(ws + 33554432);         // 4096x3072 bf16 [dead after attn]
    u16*   ctxB  = (u16*)(ws + 58720256);         // 4096x1024 bf16
    float* xmid  = (float*)(ws + 67108864);       // 4096x1024 f32
    u16*   h2    = (u16*)(ws + 83886080);         // 4096x1024 bf16
    u16*   actB  = (u16*)(ws + 92274688);         // 4096x4096 bf16
    u16*   vT    = (u16*)(ws + 25165824);         // 8 MB, reuses h1 region
    float* part  = (float*)(ws + 25165824);       // W2 partials (h1+qkvB region)
    float* partO = (float*)(ws + 92274688);       // Wo partials (actB region)

    qkvT_k<<<dim3(16, 48), 256, 0, stream>>>(Wq, Wk, Wv, bqkvT);
    transT_k<<<dim3(16, 16), 256, 0, stream>>>(Wo, woT, 1024, 1024);
    transT_k<<<dim3(64, 16), 256, 0, stream>>>(W1, w1T, 4096, 1024);
    transT_k<<<dim3(16, 64), 256, 0, stream>>>(W2, w2T, 1024, 4096);

    rmsnorm_k<<<4096, 256, 0, stream>>>(x, g1, h1);

    gemm_bt_k<0><<<dim3(24, 32), 256, 0, stream>>>(h1, bqkvT, qkvB, nullptr, nullptr,
                                                   4096, 3072, 1024, 1024);
    vtrans_k<<<dim3(32, 32), 256, 0, stream>>>(qkvB, vT);
    attn_k<<<dim3(32, 32), 256, 0, stream>>>(qkvB, vT, ctxB);

    // Wo split-K=2 -> partials, then fused add+rmsnorm
    gemm_bt_k<3><<<dim3(8, 32, 2), 256, 0, stream>>>(ctxB, woT, nullptr, partO, nullptr,
                                                     4096, 1024, 1024, 512);
    addred_norm_k<<<4096, 256, 0, stream>>>(x, partO, partO + 4096 * 1024, g2, xmid, h2);

    gemm_bt_k<2><<<dim3(32, 32), 256, 0, stream>>>(h2, w1T, actB, nullptr, nullptr,
                                                   4096, 4096, 1024, 1024);
    gemm_bt_k<3><<<dim3(8, 32, 2), 256, 0, stream>>>(actB, w2T, nullptr, part, nullptr,
                                                     4096, 1024, 4096, 2048);
    addred_k<<<4096 * 1024 / 1024, 256, 0, stream>>>(xmid, part, part + 4096 * 1024, out);
}